// Round 1
// baseline (188.583 us; speedup 1.0000x reference)
//
#include <hip/hip_runtime.h>
#include <stdint.h>

typedef __attribute__((ext_vector_type(8))) short short8;
typedef __attribute__((ext_vector_type(4))) float f32x4;
typedef __attribute__((ext_vector_type(4))) float float4v;
typedef __attribute__((ext_vector_type(4))) unsigned short u16x4;
typedef __attribute__((ext_vector_type(8))) unsigned short u16x8;

#define AS1 __attribute__((address_space(1)))
#define AS3 __attribute__((address_space(3)))

// B=4, C=512, Lf=8192, A=6. N = 49152.
// d_out: obj [4][49152] @0, reg [4][49152][2] @196608 fl, anchors @589824 fl.
// ws layout (bytes):
//   wAf   @ 0        : bf16 pre-fragmented conv weights, chunk id =
//                      (cb*3+t)*16+kc, 512 elems/chunk, lane i of chunk holds
//                      A[cout=cb*16+(i&15)][cin=kc*32+(i>>4)*8 .. +8]  (1,572,864)
//   hwp   @ 1572864  : bf16 [32][512], rows 0-5 obj_w, 6-17 reg_w, rest 0 (32,768)
//   featT @ 1605632  : bf16 [4][8208][512], row r holds l=r-1;
//                      rows 0 and 8193 zeroed (SAME pad), 8194+ slop (33,619,968)

__device__ __forceinline__ unsigned short f2bf(float f) {
    union { float f; unsigned int u; } v; v.f = f;
    unsigned int r = v.u + 0x7fffu + ((v.u >> 16) & 1u);
    return (unsigned short)(r >> 16);
}

__constant__ float c_AL[6] = {2.f, 4.f, 6.f, 9.f, 13.f, 18.f};

// blocks [0,4096): 64x64 transpose tiles.  blocks [4096,9744): prep work
// (weights repack, anchors, pad rows, and out bias pre-init for the
// atomic-accumulate conv epilogue).
__global__ __launch_bounds__(256) void prep_transpose_kernel(
    const float* __restrict__ feat, const float* __restrict__ conv_w,
    const float* __restrict__ obj_w, const float* __restrict__ reg_w,
    const float* __restrict__ obj_b, const float* __restrict__ reg_b,
    unsigned short* __restrict__ wAf, unsigned short* __restrict__ hwp,
    unsigned short* __restrict__ featT, float* __restrict__ out) {
    __shared__ unsigned short tile[64][68];   // bf16 [c][l], pad 68
    unsigned int bx = blockIdx.x;
    int tid = threadIdx.x;
    if (bx < 4096u) {
        int l0 = (bx & 127) * 64, c0 = ((bx >> 7) & 7) * 64, b = bx >> 10;
        const float* fb = feat + ((size_t)b * 512 + c0) * 8192 + l0;
        #pragma unroll
        for (int it = 0; it < 4; ++it) {
            int slot = it * 256 + tid;
            int c = slot >> 4, l4 = (slot & 15) << 2;
            float4v v = *(const float4v*)(fb + (size_t)c * 8192 + l4);
            u16x4 pk;
            pk.x = f2bf(v.x); pk.y = f2bf(v.y);
            pk.z = f2bf(v.z); pk.w = f2bf(v.w);
            *(u16x4*)(&tile[c][l4]) = pk;
        }
        __syncthreads();
        unsigned short* ftb = featT + ((size_t)b * 8208 + 1 + l0) * 512 + c0;
        #pragma unroll
        for (int it = 0; it < 2; ++it) {
            int slot = it * 256 + tid;
            int l = slot >> 3, c8 = (slot & 7) << 3;
            u16x8 pk;
            #pragma unroll
            for (int j = 0; j < 8; ++j) pk[j] = tile[c8 + j][l];
            *(u16x8*)(ftb + (size_t)l * 512 + c8) = pk;
        }
        return;
    }
    unsigned int idx = (bx - 4096u) * 256 + tid;
    if (idx < 786432u) {
        // fragment-major conv weights
        unsigned int chunkid = idx >> 9;            // 0..1535
        unsigned int within = idx & 511u;
        unsigned int lane = within >> 3, j = within & 7u;
        unsigned int kc = chunkid & 15u;
        unsigned int ct = chunkid >> 4;             // cb*3 + t
        unsigned int t = ct % 3u, cb = ct / 3u;
        unsigned int cout = cb * 16u + (lane & 15u);
        unsigned int cin = kc * 32u + (lane >> 4) * 8u + j;
        wAf[idx] = f2bf(conv_w[(cout * 512u + cin) * 3u + t]);
    } else if (idx < 802816u) {
        unsigned int i2 = idx - 786432u;
        unsigned int j = i2 >> 9, c = i2 & 511u;
        float v = 0.f;
        if (j < 6u) v = obj_w[j * 512u + c];
        else if (j < 18u) v = reg_w[(j - 6u) * 512u + c];
        hwp[i2] = f2bf(v);
    } else if (idx < 851968u) {
        unsigned int n = idx - 802816u;
        unsigned int l = n / 6u, a = n - l * 6u;
        float ctr = (float)l + 0.5f, half = 0.5f * c_AL[a];
        float* anchors = out + 589824;
        anchors[2 * n]     = ctr - half;
        anchors[2 * n + 1] = ctr + half;
    } else if (idx < 856064u) {
        unsigned int i4 = idx - 851968u;
        unsigned int b = i4 >> 10, rem = i4 & 1023u;
        unsigned int row = (rem >> 9) ? 8193u : 0u;
        unsigned int c = rem & 511u;
        featT[((size_t)b * 8208 + row) * 512 + c] = 0;
    } else if (idx < 1052672u) {
        // obj bias pre-init: out[i] = obj_b[i % 6]  (49152 % 6 == 0)
        unsigned int i5 = idx - 856064u;
        out[i5] = obj_b[i5 % 6u];
    } else {                                        // idx < 1445888
        // reg bias pre-init: out[196608 + i] = reg_b[i % 12]
        unsigned int i6 = idx - 1052672u;
        out[196608u + i6] = reg_b[i6 % 12u];
    }
}

// Conv GEMM, 256x256 tile, 8 waves (512 thr), 3 tap-phases per K-chunk.
// Double-buffered 65KB LDS stages per kc: chunks 0..16 = B rows
// [l0 .. l0+271] x 32 cin (row-major [272][32] bf16, 64B rows), chunks
// 17..64 = A fragment chunks (t*16+rb).  Counted s_waitcnt vmcnt(6)
// (per-wave shares are uniform: ph0=6, ph1=1, ph2=1, +1 for wave0) keeps
// next-kc loads in flight across barriers (T3+T4); setprio(1) around the
// 32-MFMA cluster (T5).  Epilogue: bias+relu -> bf16 htile [256][136],
// heads mini-GEMM per 128-cout half, atomicAdd into bias-pre-inited out.
__global__ __launch_bounds__(512, 2) void conv_gemm_kernel(
    const unsigned short* __restrict__ wAf,
    const unsigned short* __restrict__ featT,
    const float* __restrict__ conv_b,
    const unsigned short* __restrict__ hwp,
    float* __restrict__ out) {
    extern __shared__ __align__(16) unsigned short smem[];  // 2 x 33280 shorts

    const int tid = threadIdx.x;
    const int wave = tid >> 6, lane = tid & 63;
    const int lq = lane >> 4, lr = lane & 15;
    const int wm = wave >> 2, wn = wave & 3;
    const int l0 = blockIdx.x * 256;
    const int m0 = blockIdx.y * 256;
    const int b = blockIdx.z;
    const unsigned short* ftb = featT + (size_t)b * 8208 * 512;

    auto stage_chunk = [&](int ci, int kc2, unsigned short* bufp) {
        const unsigned short* g;
        if (ci < 17) {
            // B chunk: 16 feat rows x 32 cin; lane -> row (lane>>2), col (lane&3)*8
            g = ftb + (size_t)(l0 + ci * 16 + (lane >> 2)) * 512 + kc2 * 32 + (lane & 3) * 8;
        } else {
            int a = ci - 17;
            int t = a >> 4, rb = a & 15;
            g = wAf + ((size_t)((((m0 >> 4) + rb) * 3 + t) * 16 + kc2)) * 512 + lane * 8;
        }
        __builtin_amdgcn_global_load_lds((const AS1 void*)g,
                                         (AS3 void*)(bufp + ci * 512), 16, 0, 0);
    };

    f32x4 acc[8][4];
    #pragma unroll
    for (int i = 0; i < 8; ++i)
        #pragma unroll
        for (int j = 0; j < 4; ++j)
            acc[i][j] = (f32x4){0.f, 0.f, 0.f, 0.f};

    // prologue: stage kc=0 into buffer 0 (per-wave share = 8, wave0 = 9)
    for (int ci = wave; ci < 65; ci += 8) stage_chunk(ci, 0, smem);
    asm volatile("s_waitcnt vmcnt(0)" ::: "memory");
    __builtin_amdgcn_s_barrier();
    asm volatile("" ::: "memory");

    for (int kc = 0; kc < 16; ++kc) {
        unsigned short* cur = smem + (kc & 1) * 33280;
        unsigned short* nxt = smem + ((kc & 1) ^ 1) * 33280;
        // ---- ph0: issue 6 staging chunks for kc+1, counted wait on kc's loads
        if (kc < 15) {
            #pragma unroll
            for (int s = 0; s < 6; ++s) stage_chunk(wave + s * 8, kc + 1, nxt);
            asm volatile("s_waitcnt vmcnt(6)" ::: "memory");
        } else {
            asm volatile("s_waitcnt vmcnt(0)" ::: "memory");
        }
        __builtin_amdgcn_s_barrier();
        asm volatile("" ::: "memory");
        #pragma unroll
        for (int t = 0; t < 3; ++t) {
            if (t == 1 && kc < 15) stage_chunk(wave + 48, kc + 1, nxt);
            if (t == 2 && kc < 15) {
                stage_chunk(wave + 56, kc + 1, nxt);
                if (wave == 0) stage_chunk(64, kc + 1, nxt);
            }
            short8 af[8], bf[4];
            #pragma unroll
            for (int fm = 0; fm < 8; ++fm)
                af[fm] = *(const short8*)(cur + ((17 + t * 16 + wm * 8 + fm) << 9) + (lane << 3));
            #pragma unroll
            for (int fn = 0; fn < 4; ++fn) {
                int R = wn * 64 + fn * 16 + lr + t;   // tap-shifted B row
                bf[fn] = *(const short8*)(cur + R * 32 + lq * 8);
            }
            __builtin_amdgcn_s_setprio(1);
            #pragma unroll
            for (int fm = 0; fm < 8; ++fm)
                #pragma unroll
                for (int fn = 0; fn < 4; ++fn)
                    acc[fm][fn] = __builtin_amdgcn_mfma_f32_16x16x32_bf16(
                        af[fm], bf[fn], acc[fm][fn], 0, 0, 0);
            __builtin_amdgcn_s_setprio(0);
        }
        __builtin_amdgcn_s_barrier();   // reads of cur done before cur is restaged
        asm volatile("" ::: "memory");
    }

    // ---- epilogue: heads over two 128-cout halves, htile [256][136] bf16
    f32x4 hacc[2][2];
    #pragma unroll
    for (int i = 0; i < 2; ++i) {
        hacc[i][0] = (f32x4){0.f, 0.f, 0.f, 0.f};
        hacc[i][1] = (f32x4){0.f, 0.f, 0.f, 0.f};
    }
    #pragma unroll
    for (int mh = 0; mh < 2; ++mh) {
        if (wm == mh) {
            #pragma unroll
            for (int fm = 0; fm < 8; ++fm) {
                int mb = fm * 16 + lq * 4;           // local cout 0..127
                int cg = m0 + mh * 128 + mb;
                float cb0 = conv_b[cg];
                float cb1 = conv_b[cg + 1];
                float cb2 = conv_b[cg + 2];
                float cb3 = conv_b[cg + 3];
                #pragma unroll
                for (int fn = 0; fn < 4; ++fn) {
                    int n = wn * 64 + fn * 16 + lr;  // local l 0..255
                    f32x4 v = acc[fm][fn];
                    u16x4 pk;
                    pk.x = f2bf(fmaxf(v.x + cb0, 0.f));
                    pk.y = f2bf(fmaxf(v.y + cb1, 0.f));
                    pk.z = f2bf(fmaxf(v.z + cb2, 0.f));
                    pk.w = f2bf(fmaxf(v.w + cb3, 0.f));
                    *(u16x4*)(smem + n * 136 + mb) = pk;
                }
            }
        }
        __builtin_amdgcn_s_barrier();
        asm volatile("" ::: "memory");
        #pragma unroll
        for (int kk = 0; kk < 4; ++kk) {
            short8 ha[2], hb2[2];
            #pragma unroll
            for (int fm2 = 0; fm2 < 2; ++fm2)
                ha[fm2] = *(const short8*)(smem + (wave * 32 + fm2 * 16 + lr) * 136 + kk * 32 + lq * 8);
            #pragma unroll
            for (int fn = 0; fn < 2; ++fn)
                hb2[fn] = *(const short8*)(hwp + (size_t)(fn * 16 + lr) * 512 + m0 + mh * 128 + kk * 32 + lq * 8);
            #pragma unroll
            for (int fm2 = 0; fm2 < 2; ++fm2)
                #pragma unroll
                for (int fn = 0; fn < 2; ++fn)
                    hacc[fm2][fn] = __builtin_amdgcn_mfma_f32_16x16x32_bf16(
                        ha[fm2], hb2[fn], hacc[fm2][fn], 0, 0, 0);
        }
        __builtin_amdgcn_s_barrier();
        asm volatile("" ::: "memory");
    }
    // atomic accumulate into bias-pre-inited out (2 m-blocks per address)
    float* ob = out + (size_t)b * 49152;
    float* rg = out + 196608 + (size_t)b * 98304;
    #pragma unroll
    for (int fn = 0; fn < 2; ++fn) {
        int j = fn * 16 + lr;
        if (j < 18) {
            #pragma unroll
            for (int fm2 = 0; fm2 < 2; ++fm2)
                #pragma unroll
                for (int r = 0; r < 4; ++r) {
                    int l = l0 + wave * 32 + fm2 * 16 + lq * 4 + r;
                    float v = hacc[fm2][fn][r];
                    if (j < 6) atomicAdd(ob + (size_t)l * 6 + j, v);
                    else       atomicAdd(rg + (size_t)l * 12 + (j - 6), v);
                }
        }
    }
}

extern "C" void kernel_launch(void* const* d_in, const int* in_sizes, int n_in,
                              void* d_out, int out_size, void* d_ws, size_t ws_size,
                              hipStream_t stream) {
    const float* feat   = (const float*)d_in[0];
    const float* conv_w = (const float*)d_in[1];
    const float* conv_b = (const float*)d_in[2];
    const float* obj_w  = (const float*)d_in[3];
    const float* obj_b  = (const float*)d_in[4];
    const float* reg_w  = (const float*)d_in[5];
    const float* reg_b  = (const float*)d_in[6];
    float* out = (float*)d_out;
    char* ws = (char*)d_ws;
    unsigned short* wAf   = (unsigned short*)(ws);
    unsigned short* hwp   = (unsigned short*)(ws + 1572864);
    unsigned short* featT = (unsigned short*)(ws + 1605632);

    static bool attr_done = false;
    if (!attr_done) {
        hipFuncSetAttribute(reinterpret_cast<const void*>(conv_gemm_kernel),
                            hipFuncAttributeMaxDynamicSharedMemorySize, 133120);
        attr_done = true;
    }

    prep_transpose_kernel<<<dim3(9744), dim3(256), 0, stream>>>(
        feat, conv_w, obj_w, reg_w, obj_b, reg_b, wAf, hwp, featT, out);
    conv_gemm_kernel<<<dim3(32, 2, 4), dim3(512), 133120, stream>>>(
        wAf, featT, conv_b, hwp, out);
}